// Round 1
// baseline (1328.837 us; speedup 1.0000x reference)
//
#include <hip/hip_runtime.h>

#define FDIM 128  // feature dim == hidden dim

// ---------------------------------------------------------------------------
// 1) per-column sum / sumsq partials (atomics into zeroed buffers)
__global__ void col_stats_kernel(const float* __restrict__ x, int N,
                                 float* __restrict__ sum, float* __restrict__ sumsq) {
    int col = threadIdx.x;  // 0..127
    float s = 0.f, sq = 0.f;
    for (int r = blockIdx.x; r < N; r += gridDim.x) {
        float v = x[(size_t)r * FDIM + col];
        s += v;
        sq += v * v;
    }
    unsafeAtomicAdd(&sum[col], s);
    unsafeAtomicAdd(&sumsq[col], sq);
}

// 2) mean / rstd (ddof=1)
__global__ void finalize_stats(const float* __restrict__ sum, const float* __restrict__ sumsq,
                               int N, float* __restrict__ mean, float* __restrict__ rstd) {
    int j = threadIdx.x;
    float m = sum[j] / (float)N;
    float var = (sumsq[j] - (float)N * m * m) / (float)(N - 1);
    mean[j] = m;
    rstd[j] = rsqrtf(var);
}

// 3) W1' = W1 scaled by rstd rows; bias0 = -mean^T @ W1'
__global__ void weight_transform(const float* __restrict__ W1,
                                 const float* __restrict__ mean,
                                 const float* __restrict__ rstd,
                                 float* __restrict__ W1p, float* __restrict__ bias0) {
    int h = threadIdx.x;  // 0..127
    float acc = 0.f;
    for (int j = 0; j < FDIM; ++j) {
        float w = W1[j * FDIM + h] * rstd[j];
        W1p[j * FDIM + h] = w;
        acc += mean[j] * w;
    }
    bias0[h] = -acc;
}

// 4) degree count at dst
__global__ void deg_count(const int* __restrict__ dst, int E, float* __restrict__ deg) {
    int e = blockIdx.x * blockDim.x + threadIdx.x;
    if (e < E) unsafeAtomicAdd(&deg[dst[e]], 1.0f);
}

// 5) dinv = rsqrt(deg+1), in place
__global__ void dinv_kernel(float* __restrict__ deg, int N) {
    int i = blockIdx.x * blockDim.x + threadIdx.x;
    if (i < N) deg[i] = rsqrtf(deg[i] + 1.0f);
}

// ---------------------------------------------------------------------------
// 6) fp32 GEMM: C[M x 128] = act(A[M x 128]) @ W[128 x 128] (+ bias)
//    32-row tile / 256 threads; W staged in LDS in two 64-k halves (48 KB LDS).
template <bool RELU>
__global__ __launch_bounds__(256) void gemm128(const float* __restrict__ A,
                                               const float* __restrict__ W,
                                               const float* __restrict__ bias,
                                               float* __restrict__ C, int M) {
    __shared__ float Ws[64 * FDIM];  // 32 KB (one k-half of W)
    __shared__ float Xs[32 * FDIM];  // 16 KB (32-row A tile)
    const int tid = threadIdx.x;
    const int row0 = blockIdx.x * 32;

    // stage A tile (relu on load for layer 2)
    for (int i = tid; i < 32 * FDIM / 4; i += 256) {
        int r = row0 + (i >> 5);
        float4 v = make_float4(0.f, 0.f, 0.f, 0.f);
        if (r < M) v = ((const float4*)A)[(size_t)r * 32 + (i & 31)];
        if (RELU) {
            v.x = fmaxf(v.x, 0.f); v.y = fmaxf(v.y, 0.f);
            v.z = fmaxf(v.z, 0.f); v.w = fmaxf(v.w, 0.f);
        }
        ((float4*)Xs)[i] = v;
    }

    const int tx = tid & 31;  // column group: cols 4*tx .. 4*tx+3
    const int ty = tid >> 5;  // row group: rows ty*4 .. ty*4+3
    float acc[4][4] = {{0.f}};

    for (int half = 0; half < 2; ++half) {
        __syncthreads();  // protects Ws reuse; also orders Xs stores (half 0)
        for (int i = tid; i < 64 * FDIM / 4; i += 256)
            ((float4*)Ws)[i] = ((const float4*)W)[half * (64 * FDIM / 4) + i];
        __syncthreads();
        const int kbase = half * 64;
        for (int k = 0; k < 64; k += 4) {
            float4 wv[4];
#pragma unroll
            for (int kk = 0; kk < 4; ++kk)
                wv[kk] = *(const float4*)&Ws[(k + kk) * FDIM + tx * 4];
#pragma unroll
            for (int rr = 0; rr < 4; ++rr) {
                float4 xv = *(const float4*)&Xs[(ty * 4 + rr) * FDIM + kbase + k];
                float xk[4] = {xv.x, xv.y, xv.z, xv.w};
#pragma unroll
                for (int kk = 0; kk < 4; ++kk) {
                    acc[rr][0] = fmaf(xk[kk], wv[kk].x, acc[rr][0]);
                    acc[rr][1] = fmaf(xk[kk], wv[kk].y, acc[rr][1]);
                    acc[rr][2] = fmaf(xk[kk], wv[kk].z, acc[rr][2]);
                    acc[rr][3] = fmaf(xk[kk], wv[kk].w, acc[rr][3]);
                }
            }
        }
    }

    float4 bv = make_float4(0.f, 0.f, 0.f, 0.f);
    if (bias) bv = *(const float4*)&bias[tx * 4];
#pragma unroll
    for (int rr = 0; rr < 4; ++rr) {
        int r = row0 + ty * 4 + rr;
        if (r < M) {
            float4 o = make_float4(acc[rr][0] + bv.x, acc[rr][1] + bv.y,
                                   acc[rr][2] + bv.z, acc[rr][3] + bv.w);
            *(float4*)&C[(size_t)r * FDIM + tx * 4] = o;
        }
    }
}

// ---------------------------------------------------------------------------
// 7) out = xw * dinv^2 + b   (self-loop term; also serves as zero-init)
__global__ void init_self(const float* __restrict__ xw, const float* __restrict__ dinv,
                          const float* __restrict__ bvec, float* __restrict__ out,
                          long total4) {
    long t = (long)blockIdx.x * blockDim.x + threadIdx.x;
    if (t >= total4) return;
    int node = (int)(t >> 5);  // 32 float4 per row
    int h4 = (int)(t & 31);
    float dv = dinv[node];
    float d2 = dv * dv;
    float4 v = ((const float4*)xw)[t];
    float4 b = ((const float4*)bvec)[h4];
    float4 o = make_float4(v.x * d2 + b.x, v.y * d2 + b.y, v.z * d2 + b.z, v.w * d2 + b.w);
    ((float4*)out)[t] = o;
}

// 8) edge scatter: out[dst] += xw[src] * dinv[src]*dinv[dst]   (2 edges / block)
__global__ __launch_bounds__(256) void scatter_kernel(const float* __restrict__ xw,
                                                      const int* __restrict__ src,
                                                      const int* __restrict__ dst,
                                                      const float* __restrict__ dinv,
                                                      float* __restrict__ out, int E) {
    int e = blockIdx.x * 2 + (threadIdx.x >> 7);
    if (e >= E) return;
    int h = threadIdx.x & 127;
    int s = src[e], d = dst[e];
    float c = dinv[s] * dinv[d];
    unsafeAtomicAdd(&out[(size_t)d * FDIM + h], xw[(size_t)s * FDIM + h] * c);
}

// 9) pooled = segment_sum(relu(h), batch)  — batch is sorted, so running-acc + flush
__global__ void pool_kernel(const float* __restrict__ h, const int* __restrict__ batch,
                            float* __restrict__ out, int N) {
    int t = threadIdx.x;  // column
    int chunk = (N + gridDim.x - 1) / gridDim.x;
    int r0 = blockIdx.x * chunk;
    int r1 = min(r0 + chunk, N);
    if (r0 >= r1) return;
    float acc = 0.f;
    int curg = batch[r0];
    for (int r = r0; r < r1; ++r) {
        int g = batch[r];
        if (g != curg) {
            unsafeAtomicAdd(&out[curg * FDIM + t], acc);
            acc = 0.f;
            curg = g;
        }
        acc += fmaxf(h[(size_t)r * FDIM + t], 0.f);
    }
    unsafeAtomicAdd(&out[curg * FDIM + t], acc);
}

// ---------------------------------------------------------------------------
extern "C" void kernel_launch(void* const* d_in, const int* in_sizes, int n_in,
                              void* d_out, int out_size, void* d_ws, size_t ws_size,
                              hipStream_t stream) {
    const float* x = (const float*)d_in[0];
    const int* ei = (const int*)d_in[1];
    const int* batch = (const int*)d_in[2];
    // d_in[3] = num_graphs (unused; G = out_size / 128)
    const float* W1 = (const float*)d_in[4];
    const float* b1 = (const float*)d_in[5];
    const float* W2 = (const float*)d_in[6];
    const float* b2 = (const float*)d_in[7];

    const int N = in_sizes[2];
    const int E = in_sizes[1] / 2;
    const int* srcp = ei;
    const int* dstp = ei + E;

    float* ws = (float*)d_ws;
    const size_t NF = (size_t)N * FDIM;
    float* bufA = ws;            // N*128  (xw)
    float* bufB = bufA + NF;     // N*128  (aggregated / h)
    float* deg = bufB + NF;      // N      (deg -> dinv in place)
    float* sum = deg + N;        // 128
    float* sumsq = sum + FDIM;   // 128
    float* mean = sumsq + FDIM;  // 128
    float* rstd = mean + FDIM;   // 128
    float* W1p = rstd + FDIM;    // 128*128
    float* bias0 = W1p + FDIM * FDIM;  // 128

    // zero: deg + sum + sumsq are contiguous; d_out re-poisoned each call
    hipMemsetAsync(deg, 0, ((size_t)N + 2 * FDIM) * sizeof(float), stream);
    hipMemsetAsync(d_out, 0, (size_t)out_size * sizeof(float), stream);

    col_stats_kernel<<<256, FDIM, 0, stream>>>(x, N, sum, sumsq);
    deg_count<<<(E + 255) / 256, 256, 0, stream>>>(dstp, E, deg);
    finalize_stats<<<1, FDIM, 0, stream>>>(sum, sumsq, N, mean, rstd);
    weight_transform<<<1, FDIM, 0, stream>>>(W1, mean, rstd, W1p, bias0);
    dinv_kernel<<<(N + 255) / 256, 256, 0, stream>>>(deg, N);

    const long total4 = (long)N * 32;
    const int initGrid = (int)((total4 + 255) / 256);

    // ---- layer 1
    gemm128<false><<<(N + 31) / 32, 256, 0, stream>>>(x, W1p, bias0, bufA, N);
    init_self<<<initGrid, 256, 0, stream>>>(bufA, deg, b1, bufB, total4);
    scatter_kernel<<<(E + 1) / 2, 256, 0, stream>>>(bufA, srcp, dstp, deg, bufB, E);

    // ---- layer 2 (relu fused into GEMM load)
    gemm128<true><<<(N + 31) / 32, 256, 0, stream>>>(bufB, W2, nullptr, bufA, N);
    init_self<<<initGrid, 256, 0, stream>>>(bufA, deg, b2, bufB, total4);
    scatter_kernel<<<(E + 1) / 2, 256, 0, stream>>>(bufA, srcp, dstp, deg, bufB, E);

    // ---- pool (relu fused into load)
    pool_kernel<<<1024, FDIM, 0, stream>>>(bufB, batch, (float*)d_out, N);
}

// Round 2
// 1245.611 us; speedup vs baseline: 1.0668x; 1.0668x over previous
//
#include <hip/hip_runtime.h>

#define FDIM 128  // feature dim == hidden dim

// ---------------------------------------------------------------------------
// 1) per-column sum / sumsq partials — grid-saturating float4 sweep.
//    Thread t handles columns 4*(t&31)..+3, row-group (t>>5); 8 rows/block/iter.
//    Block-level LDS reduction, then 256 atomics/block into sum/sumsq.
__global__ __launch_bounds__(256) void col_stats_kernel(const float* __restrict__ x, int N,
                                                        float* __restrict__ sum,
                                                        float* __restrict__ sumsq) {
    const int c4 = threadIdx.x & 31;   // column group (4 cols)
    const int rg = threadIdx.x >> 5;   // row group 0..7
    float4 s = make_float4(0.f, 0.f, 0.f, 0.f);
    float4 q = make_float4(0.f, 0.f, 0.f, 0.f);
    for (long r = (long)blockIdx.x * 8 + rg; r < N; r += (long)gridDim.x * 8) {
        float4 v = ((const float4*)x)[r * 32 + c4];
        s.x += v.x; s.y += v.y; s.z += v.z; s.w += v.w;
        q.x += v.x * v.x; q.y += v.y * v.y; q.z += v.z * v.z; q.w += v.w * v.w;
    }
    __shared__ float red[8][32][8];  // [rg][c4][8 partials] = 8 KB
    float* p = red[rg][c4];
    p[0] = s.x; p[1] = s.y; p[2] = s.z; p[3] = s.w;
    p[4] = q.x; p[5] = q.y; p[6] = q.z; p[7] = q.w;
    __syncthreads();
    if (rg == 0) {
#pragma unroll
        for (int g = 1; g < 8; ++g) {
            const float* o = red[g][c4];
#pragma unroll
            for (int j = 0; j < 8; ++j) red[0][c4][j] += o[j];
        }
        const float* r0 = red[0][c4];
        unsafeAtomicAdd(&sum[c4 * 4 + 0], r0[0]);
        unsafeAtomicAdd(&sum[c4 * 4 + 1], r0[1]);
        unsafeAtomicAdd(&sum[c4 * 4 + 2], r0[2]);
        unsafeAtomicAdd(&sum[c4 * 4 + 3], r0[3]);
        unsafeAtomicAdd(&sumsq[c4 * 4 + 0], r0[4]);
        unsafeAtomicAdd(&sumsq[c4 * 4 + 1], r0[5]);
        unsafeAtomicAdd(&sumsq[c4 * 4 + 2], r0[6]);
        unsafeAtomicAdd(&sumsq[c4 * 4 + 3], r0[7]);
    }
}

// 2) mean / rstd (ddof=1)
__global__ void finalize_stats(const float* __restrict__ sum, const float* __restrict__ sumsq,
                               int N, float* __restrict__ mean, float* __restrict__ rstd) {
    int j = threadIdx.x;
    float m = sum[j] / (float)N;
    float var = (sumsq[j] - (float)N * m * m) / (float)(N - 1);
    mean[j] = m;
    rstd[j] = rsqrtf(var);
}

// 3) W1' = W1 scaled by rstd rows; bias0 = -mean^T @ W1'
__global__ void weight_transform(const float* __restrict__ W1,
                                 const float* __restrict__ mean,
                                 const float* __restrict__ rstd,
                                 float* __restrict__ W1p, float* __restrict__ bias0) {
    int h = threadIdx.x;  // 0..127
    float acc = 0.f;
    for (int j = 0; j < FDIM; ++j) {
        float w = W1[j * FDIM + h] * rstd[j];
        W1p[j * FDIM + h] = w;
        acc += mean[j] * w;
    }
    bias0[h] = -acc;
}

// 4) degree count at dst
__global__ void deg_count(const int* __restrict__ dst, int E, float* __restrict__ deg) {
    int e = blockIdx.x * blockDim.x + threadIdx.x;
    if (e < E) unsafeAtomicAdd(&deg[dst[e]], 1.0f);
}

// 5) dinv = rsqrt(deg+1), in place
__global__ void dinv_kernel(float* __restrict__ deg, int N) {
    int i = blockIdx.x * blockDim.x + threadIdx.x;
    if (i < N) deg[i] = rsqrtf(deg[i] + 1.0f);
}

// ---------------------------------------------------------------------------
// 6) fp32 GEMM: C[M x 128] = act(A[M x 128]) @ W[128 x 128] (+ bias)
//    32-row tile / 256 threads; W staged in LDS in two 64-k halves (48 KB LDS).
template <bool RELU>
__global__ __launch_bounds__(256) void gemm128(const float* __restrict__ A,
                                               const float* __restrict__ W,
                                               const float* __restrict__ bias,
                                               float* __restrict__ C, int M) {
    __shared__ float Ws[64 * FDIM];  // 32 KB (one k-half of W)
    __shared__ float Xs[32 * FDIM];  // 16 KB (32-row A tile)
    const int tid = threadIdx.x;
    const int row0 = blockIdx.x * 32;

    // stage A tile (relu on load for layer 2)
    for (int i = tid; i < 32 * FDIM / 4; i += 256) {
        int r = row0 + (i >> 5);
        float4 v = make_float4(0.f, 0.f, 0.f, 0.f);
        if (r < M) v = ((const float4*)A)[(size_t)r * 32 + (i & 31)];
        if (RELU) {
            v.x = fmaxf(v.x, 0.f); v.y = fmaxf(v.y, 0.f);
            v.z = fmaxf(v.z, 0.f); v.w = fmaxf(v.w, 0.f);
        }
        ((float4*)Xs)[i] = v;
    }

    const int tx = tid & 31;  // column group: cols 4*tx .. 4*tx+3
    const int ty = tid >> 5;  // row group: rows ty*4 .. ty*4+3
    float acc[4][4] = {{0.f}};

    for (int half = 0; half < 2; ++half) {
        __syncthreads();  // protects Ws reuse; also orders Xs stores (half 0)
        for (int i = tid; i < 64 * FDIM / 4; i += 256)
            ((float4*)Ws)[i] = ((const float4*)W)[half * (64 * FDIM / 4) + i];
        __syncthreads();
        const int kbase = half * 64;
        for (int k = 0; k < 64; k += 4) {
            float4 wv[4];
#pragma unroll
            for (int kk = 0; kk < 4; ++kk)
                wv[kk] = *(const float4*)&Ws[(k + kk) * FDIM + tx * 4];
#pragma unroll
            for (int rr = 0; rr < 4; ++rr) {
                float4 xv = *(const float4*)&Xs[(ty * 4 + rr) * FDIM + kbase + k];
                float xk[4] = {xv.x, xv.y, xv.z, xv.w};
#pragma unroll
                for (int kk = 0; kk < 4; ++kk) {
                    acc[rr][0] = fmaf(xk[kk], wv[kk].x, acc[rr][0]);
                    acc[rr][1] = fmaf(xk[kk], wv[kk].y, acc[rr][1]);
                    acc[rr][2] = fmaf(xk[kk], wv[kk].z, acc[rr][2]);
                    acc[rr][3] = fmaf(xk[kk], wv[kk].w, acc[rr][3]);
                }
            }
        }
    }

    float4 bv = make_float4(0.f, 0.f, 0.f, 0.f);
    if (bias) bv = *(const float4*)&bias[tx * 4];
#pragma unroll
    for (int rr = 0; rr < 4; ++rr) {
        int r = row0 + ty * 4 + rr;
        if (r < M) {
            float4 o = make_float4(acc[rr][0] + bv.x, acc[rr][1] + bv.y,
                                   acc[rr][2] + bv.z, acc[rr][3] + bv.w);
            *(float4*)&C[(size_t)r * FDIM + tx * 4] = o;
        }
    }
}

// ---------------------------------------------------------------------------
// 7) out = xw * dinv^2 + b   (self-loop term; also serves as zero-init)
__global__ void init_self(const float* __restrict__ xw, const float* __restrict__ dinv,
                          const float* __restrict__ bvec, float* __restrict__ out,
                          long total4) {
    long t = (long)blockIdx.x * blockDim.x + threadIdx.x;
    if (t >= total4) return;
    int node = (int)(t >> 5);  // 32 float4 per row
    int h4 = (int)(t & 31);
    float dv = dinv[node];
    float d2 = dv * dv;
    float4 v = ((const float4*)xw)[t];
    float4 b = ((const float4*)bvec)[h4];
    float4 o = make_float4(v.x * d2 + b.x, v.y * d2 + b.y, v.z * d2 + b.z, v.w * d2 + b.w);
    ((float4*)out)[t] = o;
}

// 8) edge scatter: out[dst] += xw[src] * dinv[src]*dinv[dst]   (2 edges / block)
__global__ __launch_bounds__(256) void scatter_kernel(const float* __restrict__ xw,
                                                      const int* __restrict__ src,
                                                      const int* __restrict__ dst,
                                                      const float* __restrict__ dinv,
                                                      float* __restrict__ out, int E) {
    int e = blockIdx.x * 2 + (threadIdx.x >> 7);
    if (e >= E) return;
    int h = threadIdx.x & 127;
    int s = src[e], d = dst[e];
    float c = dinv[s] * dinv[d];
    unsafeAtomicAdd(&out[(size_t)d * FDIM + h], xw[(size_t)s * FDIM + h] * c);
}

// 9) pooled = segment_sum(relu(h), batch)  — batch is sorted, so running-acc + flush
__global__ void pool_kernel(const float* __restrict__ h, const int* __restrict__ batch,
                            float* __restrict__ out, int N) {
    int t = threadIdx.x;  // column
    int chunk = (N + gridDim.x - 1) / gridDim.x;
    int r0 = blockIdx.x * chunk;
    int r1 = min(r0 + chunk, N);
    if (r0 >= r1) return;
    float acc = 0.f;
    int curg = batch[r0];
    for (int r = r0; r < r1; ++r) {
        int g = batch[r];
        if (g != curg) {
            unsafeAtomicAdd(&out[curg * FDIM + t], acc);
            acc = 0.f;
            curg = g;
        }
        acc += fmaxf(h[(size_t)r * FDIM + t], 0.f);
    }
    unsafeAtomicAdd(&out[curg * FDIM + t], acc);
}

// ---------------------------------------------------------------------------
extern "C" void kernel_launch(void* const* d_in, const int* in_sizes, int n_in,
                              void* d_out, int out_size, void* d_ws, size_t ws_size,
                              hipStream_t stream) {
    const float* x = (const float*)d_in[0];
    const int* ei = (const int*)d_in[1];
    const int* batch = (const int*)d_in[2];
    // d_in[3] = num_graphs (unused; G = out_size / 128)
    const float* W1 = (const float*)d_in[4];
    const float* b1 = (const float*)d_in[5];
    const float* W2 = (const float*)d_in[6];
    const float* b2 = (const float*)d_in[7];

    const int N = in_sizes[2];
    const int E = in_sizes[1] / 2;
    const int* srcp = ei;
    const int* dstp = ei + E;

    float* ws = (float*)d_ws;
    const size_t NF = (size_t)N * FDIM;
    float* bufA = ws;            // N*128  (xw)
    float* bufB = bufA + NF;     // N*128  (aggregated / h)
    float* deg = bufB + NF;      // N      (deg -> dinv in place)
    float* sum = deg + N;        // 128
    float* sumsq = sum + FDIM;   // 128
    float* mean = sumsq + FDIM;  // 128
    float* rstd = mean + FDIM;   // 128
    float* W1p = rstd + FDIM;    // 128*128
    float* bias0 = W1p + FDIM * FDIM;  // 128

    // zero: deg + sum + sumsq are contiguous; d_out re-poisoned each call
    hipMemsetAsync(deg, 0, ((size_t)N + 2 * FDIM) * sizeof(float), stream);
    hipMemsetAsync(d_out, 0, (size_t)out_size * sizeof(float), stream);

    col_stats_kernel<<<2048, 256, 0, stream>>>(x, N, sum, sumsq);
    deg_count<<<(E + 255) / 256, 256, 0, stream>>>(dstp, E, deg);
    finalize_stats<<<1, FDIM, 0, stream>>>(sum, sumsq, N, mean, rstd);
    weight_transform<<<1, FDIM, 0, stream>>>(W1, mean, rstd, W1p, bias0);
    dinv_kernel<<<(N + 255) / 256, 256, 0, stream>>>(deg, N);

    const long total4 = (long)N * 32;
    const int initGrid = (int)((total4 + 255) / 256);

    // ---- layer 1
    gemm128<false><<<(N + 31) / 32, 256, 0, stream>>>(x, W1p, bias0, bufA, N);
    init_self<<<initGrid, 256, 0, stream>>>(bufA, deg, b1, bufB, total4);
    scatter_kernel<<<(E + 1) / 2, 256, 0, stream>>>(bufA, srcp, dstp, deg, bufB, E);

    // ---- layer 2 (relu fused into GEMM load)
    gemm128<true><<<(N + 31) / 32, 256, 0, stream>>>(bufB, W2, nullptr, bufA, N);
    init_self<<<initGrid, 256, 0, stream>>>(bufA, deg, b2, bufB, total4);
    scatter_kernel<<<(E + 1) / 2, 256, 0, stream>>>(bufA, srcp, dstp, deg, bufB, E);

    // ---- pool (relu fused into load)
    pool_kernel<<<1024, FDIM, 0, stream>>>(bufB, batch, (float*)d_out, N);
}

// Round 3
// 870.249 us; speedup vs baseline: 1.5270x; 1.4313x over previous
//
#include <hip/hip_runtime.h>

#define FDIM 128  // feature dim == hidden dim

// ---------------------------------------------------------------------------
// 1) per-column sum / sumsq partials — grid-saturating float4 sweep.
__global__ __launch_bounds__(256) void col_stats_kernel(const float* __restrict__ x, int N,
                                                        float* __restrict__ sum,
                                                        float* __restrict__ sumsq) {
    const int c4 = threadIdx.x & 31;   // column group (4 cols)
    const int rg = threadIdx.x >> 5;   // row group 0..7
    float4 s = make_float4(0.f, 0.f, 0.f, 0.f);
    float4 q = make_float4(0.f, 0.f, 0.f, 0.f);
    for (long r = (long)blockIdx.x * 8 + rg; r < N; r += (long)gridDim.x * 8) {
        float4 v = ((const float4*)x)[r * 32 + c4];
        s.x += v.x; s.y += v.y; s.z += v.z; s.w += v.w;
        q.x += v.x * v.x; q.y += v.y * v.y; q.z += v.z * v.z; q.w += v.w * v.w;
    }
    __shared__ float red[8][32][8];  // [rg][c4][8 partials] = 8 KB
    float* p = red[rg][c4];
    p[0] = s.x; p[1] = s.y; p[2] = s.z; p[3] = s.w;
    p[4] = q.x; p[5] = q.y; p[6] = q.z; p[7] = q.w;
    __syncthreads();
    if (rg == 0) {
#pragma unroll
        for (int g = 1; g < 8; ++g) {
            const float* o = red[g][c4];
#pragma unroll
            for (int j = 0; j < 8; ++j) red[0][c4][j] += o[j];
        }
        const float* r0 = red[0][c4];
        unsafeAtomicAdd(&sum[c4 * 4 + 0], r0[0]);
        unsafeAtomicAdd(&sum[c4 * 4 + 1], r0[1]);
        unsafeAtomicAdd(&sum[c4 * 4 + 2], r0[2]);
        unsafeAtomicAdd(&sum[c4 * 4 + 3], r0[3]);
        unsafeAtomicAdd(&sumsq[c4 * 4 + 0], r0[4]);
        unsafeAtomicAdd(&sumsq[c4 * 4 + 1], r0[5]);
        unsafeAtomicAdd(&sumsq[c4 * 4 + 2], r0[6]);
        unsafeAtomicAdd(&sumsq[c4 * 4 + 3], r0[7]);
    }
}

// 2) mean / rstd (ddof=1)
__global__ void finalize_stats(const float* __restrict__ sum, const float* __restrict__ sumsq,
                               int N, float* __restrict__ mean, float* __restrict__ rstd) {
    int j = threadIdx.x;
    float m = sum[j] / (float)N;
    float var = (sumsq[j] - (float)N * m * m) / (float)(N - 1);
    mean[j] = m;
    rstd[j] = rsqrtf(var);
}

// 3) W1' = W1 scaled by rstd rows; bias0 = -mean^T @ W1'
__global__ void weight_transform(const float* __restrict__ W1,
                                 const float* __restrict__ mean,
                                 const float* __restrict__ rstd,
                                 float* __restrict__ W1p, float* __restrict__ bias0) {
    int h = threadIdx.x;  // 0..127
    float acc = 0.f;
    for (int j = 0; j < FDIM; ++j) {
        float w = W1[j * FDIM + h] * rstd[j];
        W1p[j * FDIM + h] = w;
        acc += mean[j] * w;
    }
    bias0[h] = -acc;
}

// 4) degree count at dst (int)
__global__ void deg_count(const int* __restrict__ dst, int E, int* __restrict__ cnt) {
    int e = blockIdx.x * blockDim.x + threadIdx.x;
    if (e < E) atomicAdd(&cnt[dst[e]], 1);
}

// 5) dinv = rsqrt(cnt+1)
__global__ void dinv_kernel(const int* __restrict__ cnt, float* __restrict__ dinv, int N) {
    int i = blockIdx.x * blockDim.x + threadIdx.x;
    if (i < N) dinv[i] = rsqrtf((float)cnt[i] + 1.0f);
}

// 6) contiguous per-node edge ranges: block-level LDS scan + one global atomic
//    per block for the base. Node order across blocks is arbitrary (fine);
//    per-node contiguity is all the aggregation needs.
__global__ __launch_bounds__(256) void alloc_offsets(const int* __restrict__ cnt, int N,
                                                     int* __restrict__ start,
                                                     int* __restrict__ wcur,
                                                     int* __restrict__ counter) {
    __shared__ int sh[256];
    __shared__ int base;
    int i = blockIdx.x * 256 + threadIdx.x;
    int v = (i < N) ? cnt[i] : 0;
    sh[threadIdx.x] = v;
    __syncthreads();
    for (int off = 1; off < 256; off <<= 1) {
        int t = (threadIdx.x >= off) ? sh[threadIdx.x - off] : 0;
        __syncthreads();
        sh[threadIdx.x] += t;
        __syncthreads();
    }
    if (threadIdx.x == 255) base = atomicAdd(counter, sh[255]);
    __syncthreads();
    int excl = base + sh[threadIdx.x] - v;
    if (i < N) {
        start[i] = excl;
        wcur[i] = excl;
    }
}

// 7) bucket edges by dst; precompute coef = dinv[s]*dinv[d]
__global__ void fill_edges(const int* __restrict__ src, const int* __restrict__ dst,
                           const float* __restrict__ dinv, int E,
                           int* __restrict__ wcur, int* __restrict__ esrc,
                           float* __restrict__ ecoef) {
    int e = blockIdx.x * blockDim.x + threadIdx.x;
    if (e >= E) return;
    int s = src[e], d = dst[e];
    int pos = atomicAdd(&wcur[d], 1);
    esrc[pos] = s;
    ecoef[pos] = dinv[s] * dinv[d];
}

// ---------------------------------------------------------------------------
// 8) fp32 GEMM: C[M x 128] = act(A[M x 128]) @ W[128 x 128] (+ bias)
template <bool RELU>
__global__ __launch_bounds__(256) void gemm128(const float* __restrict__ A,
                                               const float* __restrict__ W,
                                               const float* __restrict__ bias,
                                               float* __restrict__ C, int M) {
    __shared__ float Ws[64 * FDIM];  // 32 KB (one k-half of W)
    __shared__ float Xs[32 * FDIM];  // 16 KB (32-row A tile)
    const int tid = threadIdx.x;
    const int row0 = blockIdx.x * 32;

    for (int i = tid; i < 32 * FDIM / 4; i += 256) {
        int r = row0 + (i >> 5);
        float4 v = make_float4(0.f, 0.f, 0.f, 0.f);
        if (r < M) v = ((const float4*)A)[(size_t)r * 32 + (i & 31)];
        if (RELU) {
            v.x = fmaxf(v.x, 0.f); v.y = fmaxf(v.y, 0.f);
            v.z = fmaxf(v.z, 0.f); v.w = fmaxf(v.w, 0.f);
        }
        ((float4*)Xs)[i] = v;
    }

    const int tx = tid & 31;
    const int ty = tid >> 5;
    float acc[4][4] = {{0.f}};

    for (int half = 0; half < 2; ++half) {
        __syncthreads();
        for (int i = tid; i < 64 * FDIM / 4; i += 256)
            ((float4*)Ws)[i] = ((const float4*)W)[half * (64 * FDIM / 4) + i];
        __syncthreads();
        const int kbase = half * 64;
        for (int k = 0; k < 64; k += 4) {
            float4 wv[4];
#pragma unroll
            for (int kk = 0; kk < 4; ++kk)
                wv[kk] = *(const float4*)&Ws[(k + kk) * FDIM + tx * 4];
#pragma unroll
            for (int rr = 0; rr < 4; ++rr) {
                float4 xv = *(const float4*)&Xs[(ty * 4 + rr) * FDIM + kbase + k];
                float xk[4] = {xv.x, xv.y, xv.z, xv.w};
#pragma unroll
                for (int kk = 0; kk < 4; ++kk) {
                    acc[rr][0] = fmaf(xk[kk], wv[kk].x, acc[rr][0]);
                    acc[rr][1] = fmaf(xk[kk], wv[kk].y, acc[rr][1]);
                    acc[rr][2] = fmaf(xk[kk], wv[kk].z, acc[rr][2]);
                    acc[rr][3] = fmaf(xk[kk], wv[kk].w, acc[rr][3]);
                }
            }
        }
    }

    float4 bv = make_float4(0.f, 0.f, 0.f, 0.f);
    if (bias) bv = *(const float4*)&bias[tx * 4];
#pragma unroll
    for (int rr = 0; rr < 4; ++rr) {
        int r = row0 + ty * 4 + rr;
        if (r < M) {
            float4 o = make_float4(acc[rr][0] + bv.x, acc[rr][1] + bv.y,
                                   acc[rr][2] + bv.z, acc[rr][3] + bv.w);
            *(float4*)&C[(size_t)r * FDIM + tx * 4] = o;
        }
    }
}

// ---------------------------------------------------------------------------
// 9) aggregation: out[d] = xw[d]*dinv[d]^2 + b + sum_{e: dst=d} xw[src]*coef
//    8 nodes / 256-thread block, 32 lanes x float4 per node. No atomics:
//    each output row written exactly once.
__global__ __launch_bounds__(256) void aggregate(const float* __restrict__ xw,
                                                 const float* __restrict__ dinv,
                                                 const int* __restrict__ start,
                                                 const int* __restrict__ cnt,
                                                 const int* __restrict__ esrc,
                                                 const float* __restrict__ ecoef,
                                                 const float* __restrict__ bvec,
                                                 float* __restrict__ out, int N) {
    int node = blockIdx.x * 8 + (threadIdx.x >> 5);
    if (node >= N) return;
    int c4 = threadIdx.x & 31;  // float4 column group
    float dv = dinv[node];
    float d2 = dv * dv;
    float4 b = ((const float4*)bvec)[c4];
    float4 v = ((const float4*)xw)[(size_t)node * 32 + c4];
    float4 acc = make_float4(fmaf(v.x, d2, b.x), fmaf(v.y, d2, b.y),
                             fmaf(v.z, d2, b.z), fmaf(v.w, d2, b.w));
    int s0 = start[node];
    int s1 = s0 + cnt[node];
    for (int j = s0; j < s1; ++j) {
        int s = esrc[j];        // broadcast within the node's 32 lanes
        float c = ecoef[j];     // broadcast
        float4 u = ((const float4*)xw)[(size_t)s * 32 + c4];
        acc.x = fmaf(u.x, c, acc.x);
        acc.y = fmaf(u.y, c, acc.y);
        acc.z = fmaf(u.z, c, acc.z);
        acc.w = fmaf(u.w, c, acc.w);
    }
    ((float4*)out)[(size_t)node * 32 + c4] = acc;
}

// 10) pooled = segment_sum(relu(h), batch) — batch sorted: running-acc + flush
__global__ void pool_kernel(const float* __restrict__ h, const int* __restrict__ batch,
                            float* __restrict__ out, int N) {
    int t = threadIdx.x;  // column
    int chunk = (N + gridDim.x - 1) / gridDim.x;
    int r0 = blockIdx.x * chunk;
    int r1 = min(r0 + chunk, N);
    if (r0 >= r1) return;
    float acc = 0.f;
    int curg = batch[r0];
    for (int r = r0; r < r1; ++r) {
        int g = batch[r];
        if (g != curg) {
            unsafeAtomicAdd(&out[curg * FDIM + t], acc);
            acc = 0.f;
            curg = g;
        }
        acc += fmaxf(h[(size_t)r * FDIM + t], 0.f);
    }
    unsafeAtomicAdd(&out[curg * FDIM + t], acc);
}

// ---------------------------------------------------------------------------
extern "C" void kernel_launch(void* const* d_in, const int* in_sizes, int n_in,
                              void* d_out, int out_size, void* d_ws, size_t ws_size,
                              hipStream_t stream) {
    const float* x = (const float*)d_in[0];
    const int* ei = (const int*)d_in[1];
    const int* batch = (const int*)d_in[2];
    const float* W1 = (const float*)d_in[4];
    const float* b1 = (const float*)d_in[5];
    const float* W2 = (const float*)d_in[6];
    const float* b2 = (const float*)d_in[7];

    const int N = in_sizes[2];
    const int E = in_sizes[1] / 2;
    const int* srcp = ei;
    const int* dstp = ei + E;

    float* ws = (float*)d_ws;
    const size_t NF = (size_t)N * FDIM;
    float* bufA = ws;                    // N*128  (xw)
    float* bufB = bufA + NF;             // N*128  (aggregated / h)
    float* dinv = bufB + NF;             // N
    int* cnt = (int*)(dinv + N);         // N      <- memset from here
    int* counter = cnt + N;              // 1
    float* sum = (float*)(counter + 1);  // 128
    float* sumsq = sum + FDIM;           // 128    <- memset to here (N+257 elems)
    float* mean = sumsq + FDIM;          // 128
    float* rstd = mean + FDIM;           // 128
    float* W1p = rstd + FDIM;            // 128*128
    float* bias0 = W1p + FDIM * FDIM;    // 128
    int* start = (int*)(bias0 + FDIM);   // N
    int* wcur = start + N;               // N
    int* esrc = wcur + N;                // E
    float* ecoef = (float*)(esrc + E);   // E

    hipMemsetAsync(cnt, 0, ((size_t)N + 1 + 2 * FDIM) * sizeof(float), stream);
    hipMemsetAsync(d_out, 0, (size_t)out_size * sizeof(float), stream);

    col_stats_kernel<<<2048, 256, 0, stream>>>(x, N, sum, sumsq);
    deg_count<<<(E + 255) / 256, 256, 0, stream>>>(dstp, E, cnt);
    finalize_stats<<<1, FDIM, 0, stream>>>(sum, sumsq, N, mean, rstd);
    weight_transform<<<1, FDIM, 0, stream>>>(W1, mean, rstd, W1p, bias0);
    dinv_kernel<<<(N + 255) / 256, 256, 0, stream>>>(cnt, dinv, N);
    alloc_offsets<<<(N + 255) / 256, 256, 0, stream>>>(cnt, N, start, wcur, counter);
    fill_edges<<<(E + 255) / 256, 256, 0, stream>>>(srcp, dstp, dinv, E, wcur, esrc, ecoef);

    const int aggGrid = (N + 7) / 8;

    // ---- layer 1 (bias0 folded into GEMM; b1 + self-loop fused into aggregate)
    gemm128<false><<<(N + 31) / 32, 256, 0, stream>>>(x, W1p, bias0, bufA, N);
    aggregate<<<aggGrid, 256, 0, stream>>>(bufA, dinv, start, cnt, esrc, ecoef, b1, bufB, N);

    // ---- layer 2 (relu fused into GEMM load)
    gemm128<true><<<(N + 31) / 32, 256, 0, stream>>>(bufB, W2, nullptr, bufA, N);
    aggregate<<<aggGrid, 256, 0, stream>>>(bufA, dinv, start, cnt, esrc, ecoef, b2, bufB, N);

    // ---- pool (relu fused into load)
    pool_kernel<<<1024, FDIM, 0, stream>>>(bufB, batch, (float*)d_out, N);
}

// Round 4
// 712.139 us; speedup vs baseline: 1.8660x; 1.2220x over previous
//
#include <hip/hip_runtime.h>

#define FDIM 128  // feature dim == hidden dim

typedef __attribute__((ext_vector_type(8))) short short8;   // 8 bf16 (4 VGPRs)
typedef __attribute__((ext_vector_type(4))) float f32x4;    // MFMA accumulator

__device__ inline unsigned short f2bf(float f) {  // round-to-nearest-even
    unsigned int u = __float_as_uint(f);
    unsigned int r = u + 0x7FFFu + ((u >> 16) & 1u);
    return (unsigned short)(r >> 16);
}

// ---------------------------------------------------------------------------
// 1) per-column sum/sumsq — grid float4 sweep, block LDS reduce, PLAIN stores
//    of per-block partials (atomic-free; round-3's 512K same-address atomics
//    onto 16 cache lines were a ~200us serialization tail).
__global__ __launch_bounds__(256) void col_stats_kernel(const float* __restrict__ x, int N,
                                                        float* __restrict__ partials) {
    const int c4 = threadIdx.x & 31;   // column group (4 cols)
    const int rg = threadIdx.x >> 5;   // row group 0..7
    float4 s = make_float4(0.f, 0.f, 0.f, 0.f);
    float4 q = make_float4(0.f, 0.f, 0.f, 0.f);
    for (long r = (long)blockIdx.x * 8 + rg; r < N; r += (long)gridDim.x * 8) {
        float4 v = ((const float4*)x)[r * 32 + c4];
        s.x += v.x; s.y += v.y; s.z += v.z; s.w += v.w;
        q.x += v.x * v.x; q.y += v.y * v.y; q.z += v.z * v.z; q.w += v.w * v.w;
    }
    __shared__ float red[8][32][8];  // [rg][c4][8 partials] = 8 KB
    float* p = red[rg][c4];
    p[0] = s.x; p[1] = s.y; p[2] = s.z; p[3] = s.w;
    p[4] = q.x; p[5] = q.y; p[6] = q.z; p[7] = q.w;
    __syncthreads();
    if (rg == 0) {
#pragma unroll
        for (int g = 1; g < 8; ++g) {
            const float* o = red[g][c4];
#pragma unroll
            for (int j = 0; j < 8; ++j) red[0][c4][j] += o[j];
        }
        const float* r0 = red[0][c4];
        float* out = &partials[(size_t)blockIdx.x * 256];
        ((float4*)out)[c4] = make_float4(r0[0], r0[1], r0[2], r0[3]);          // sum cols
        ((float4*)(out + 128))[c4] = make_float4(r0[4], r0[5], r0[6], r0[7]);  // sumsq cols
    }
}

// 2) reduce partials -> mean / rstd (ddof=1). 1024 threads: 8 groups x 128 cols.
__global__ __launch_bounds__(1024) void finalize_stats(const float* __restrict__ partials,
                                                       int nblk, int N,
                                                       float* __restrict__ mean,
                                                       float* __restrict__ rstd) {
    __shared__ float sh[8][2][FDIM];  // 8 KB
    int g = threadIdx.x >> 7;   // 0..7
    int j = threadIdx.x & 127;  // column
    float s = 0.f, q = 0.f;
    for (int b = g; b < nblk; b += 8) {
        s += partials[(size_t)b * 256 + j];
        q += partials[(size_t)b * 256 + 128 + j];
    }
    sh[g][0][j] = s;
    sh[g][1][j] = q;
    __syncthreads();
    if (g == 0) {
#pragma unroll
        for (int k = 1; k < 8; ++k) { s += sh[k][0][j]; q += sh[k][1][j]; }
        float m = s / (float)N;
        float var = (q - (float)N * m * m) / (float)(N - 1);
        mean[j] = m;
        rstd[j] = rsqrtf(var);
    }
}

// 3) WTbf[h][j] = bf16(W[j][h] * (rstd?rstd[j]:1)); optional bias0[h] = -sum_j mean[j]*w
__global__ void prep_wt(const float* __restrict__ W, const float* __restrict__ mean,
                        const float* __restrict__ rstd, unsigned short* __restrict__ WTbf,
                        float* __restrict__ bias0) {
    int h = threadIdx.x;  // 0..127
    float acc = 0.f;
    for (int j = 0; j < FDIM; ++j) {
        float w = W[j * FDIM + h];
        if (rstd) w *= rstd[j];
        WTbf[h * FDIM + j] = f2bf(w);
        if (bias0) acc += mean[j] * w;
    }
    if (bias0) bias0[h] = -acc;
}

// 4) degree count at dst (int)
__global__ void deg_count(const int* __restrict__ dst, int E, int* __restrict__ cnt) {
    int e = blockIdx.x * blockDim.x + threadIdx.x;
    if (e < E) atomicAdd(&cnt[dst[e]], 1);
}

// 5) dinv = rsqrt(cnt+1)
__global__ void dinv_kernel(const int* __restrict__ cnt, float* __restrict__ dinv, int N) {
    int i = blockIdx.x * blockDim.x + threadIdx.x;
    if (i < N) dinv[i] = rsqrtf((float)cnt[i] + 1.0f);
}

// 6) contiguous per-node edge ranges (block LDS scan + one global atomic per block)
__global__ __launch_bounds__(256) void alloc_offsets(const int* __restrict__ cnt, int N,
                                                     int* __restrict__ start,
                                                     int* __restrict__ wcur,
                                                     int* __restrict__ counter) {
    __shared__ int sh[256];
    __shared__ int base;
    int i = blockIdx.x * 256 + threadIdx.x;
    int v = (i < N) ? cnt[i] : 0;
    sh[threadIdx.x] = v;
    __syncthreads();
    for (int off = 1; off < 256; off <<= 1) {
        int t = (threadIdx.x >= off) ? sh[threadIdx.x - off] : 0;
        __syncthreads();
        sh[threadIdx.x] += t;
        __syncthreads();
    }
    if (threadIdx.x == 255) base = atomicAdd(counter, sh[255]);
    __syncthreads();
    int excl = base + sh[threadIdx.x] - v;
    if (i < N) {
        start[i] = excl;
        wcur[i] = excl;
    }
}

// 7) bucket edges by dst; precompute coef = dinv[s]*dinv[d]
__global__ void fill_edges(const int* __restrict__ src, const int* __restrict__ dst,
                           const float* __restrict__ dinv, int E,
                           int* __restrict__ wcur, int* __restrict__ esrc,
                           float* __restrict__ ecoef) {
    int e = blockIdx.x * blockDim.x + threadIdx.x;
    if (e >= E) return;
    int s = src[e], d = dst[e];
    int pos = atomicAdd(&wcur[d], 1);
    esrc[pos] = s;
    ecoef[pos] = dinv[s] * dinv[d];
}

// ---------------------------------------------------------------------------
// 8) bf16 MFMA GEMM: C[M x 128] = act(A[M x 128]) @ W[128 x 128] (+ bias)
//    A fp32 -> bf16 on LDS stage; WT is W transposed, bf16 ([n][k] rows).
//    64 rows/block, 4 waves x 16 rows; per wave 8 N-tiles x 4 K-steps of
//    mfma_f32_16x16x32_bf16. LDS stride 136 bf16: b128 reads spread uniformly
//    (8 lanes/bank-group = conflict-free optimum for 16B reads).
template <bool RELU>
__global__ __launch_bounds__(256) void gemm_mfma(const float* __restrict__ A,
                                                 const unsigned short* __restrict__ WT,
                                                 const float* __restrict__ bias,
                                                 float* __restrict__ C, int M) {
    constexpr int LDA = 136;
    __shared__ unsigned short Alds[64 * LDA];    // 17.4 KB
    __shared__ unsigned short Wlds[FDIM * LDA];  // 34.8 KB
    const int tid = threadIdx.x;
    const int row0 = blockIdx.x * 64;

    // stage WT -> LDS, 16B chunks
    for (int i = tid; i < FDIM * 16; i += 256) {
        int r = i >> 4, g = i & 15;
        *(int4*)&Wlds[r * LDA + g * 8] = *(const int4*)&WT[r * FDIM + g * 8];
    }
    // stage A -> LDS with fp32->bf16 convert (+relu for layer 2)
    for (int i = tid; i < 64 * 32; i += 256) {
        int r = i >> 5, c4 = i & 31;
        int row = row0 + r;
        float4 v = make_float4(0.f, 0.f, 0.f, 0.f);
        if (row < M) v = ((const float4*)A)[(size_t)row * 32 + c4];
        if (RELU) {
            v.x = fmaxf(v.x, 0.f); v.y = fmaxf(v.y, 0.f);
            v.z = fmaxf(v.z, 0.f); v.w = fmaxf(v.w, 0.f);
        }
        ushort4 p;
        p.x = f2bf(v.x); p.y = f2bf(v.y); p.z = f2bf(v.z); p.w = f2bf(v.w);
        *(ushort4*)&Alds[r * LDA + c4 * 4] = p;
    }
    __syncthreads();

    const int lane = tid & 63;
    const int wave = tid >> 6;
    const int m16 = lane & 15;   // A row / C col within tile
    const int quad = lane >> 4;  // 0..3

    f32x4 acc[8];
#pragma unroll
    for (int t = 0; t < 8; ++t) acc[t] = (f32x4){0.f, 0.f, 0.f, 0.f};

    const unsigned short* Abase = &Alds[(wave * 16 + m16) * LDA + quad * 8];
    const unsigned short* Wbase = &Wlds[m16 * LDA + quad * 8];
#pragma unroll
    for (int s = 0; s < 4; ++s) {
        short8 a = *(const short8*)&Abase[s * 32];
#pragma unroll
        for (int t = 0; t < 8; ++t) {
            short8 b = *(const short8*)&Wbase[t * 16 * LDA + s * 32];
            acc[t] = __builtin_amdgcn_mfma_f32_16x16x32_bf16(a, b, acc[t], 0, 0, 0);
        }
    }

    // epilogue: C/D layout col=lane&15, row=quad*4+reg
#pragma unroll
    for (int t = 0; t < 8; ++t) {
        float bv = bias ? bias[t * 16 + m16] : 0.f;
#pragma unroll
        for (int i = 0; i < 4; ++i) {
            int r = row0 + wave * 16 + quad * 4 + i;
            if (r < M) C[(size_t)r * FDIM + t * 16 + m16] = acc[t][i] + bv;
        }
    }
}

// ---------------------------------------------------------------------------
// 9) aggregation: out[d] = xw[d]*dinv[d]^2 + b + sum_{e: dst=d} xw[src]*coef
__global__ __launch_bounds__(256) void aggregate(const float* __restrict__ xw,
                                                 const float* __restrict__ dinv,
                                                 const int* __restrict__ start,
                                                 const int* __restrict__ cnt,
                                                 const int* __restrict__ esrc,
                                                 const float* __restrict__ ecoef,
                                                 const float* __restrict__ bvec,
                                                 float* __restrict__ out, int N) {
    int node = blockIdx.x * 8 + (threadIdx.x >> 5);
    if (node >= N) return;
    int c4 = threadIdx.x & 31;  // float4 column group
    float dv = dinv[node];
    float d2 = dv * dv;
    float4 b = ((const float4*)bvec)[c4];
    float4 v = ((const float4*)xw)[(size_t)node * 32 + c4];
    float4 acc = make_float4(fmaf(v.x, d2, b.x), fmaf(v.y, d2, b.y),
                             fmaf(v.z, d2, b.z), fmaf(v.w, d2, b.w));
    int s0 = start[node];
    int s1 = s0 + cnt[node];
    for (int j = s0; j < s1; ++j) {
        int s = esrc[j];
        float c = ecoef[j];
        float4 u = ((const float4*)xw)[(size_t)s * 32 + c4];
        acc.x = fmaf(u.x, c, acc.x);
        acc.y = fmaf(u.y, c, acc.y);
        acc.z = fmaf(u.z, c, acc.z);
        acc.w = fmaf(u.w, c, acc.w);
    }
    ((float4*)out)[(size_t)node * 32 + c4] = acc;
}

// 10) pooled = segment_sum(relu(h), batch) — batch sorted: running-acc + flush
__global__ void pool_kernel(const float* __restrict__ h, const int* __restrict__ batch,
                            float* __restrict__ out, int N) {
    int t = threadIdx.x;  // column
    int chunk = (N + gridDim.x - 1) / gridDim.x;
    int r0 = blockIdx.x * chunk;
    int r1 = min(r0 + chunk, N);
    if (r0 >= r1) return;
    float acc = 0.f;
    int curg = batch[r0];
    for (int r = r0; r < r1; ++r) {
        int g = batch[r];
        if (g != curg) {
            unsafeAtomicAdd(&out[curg * FDIM + t], acc);
            acc = 0.f;
            curg = g;
        }
        acc += fmaxf(h[(size_t)r * FDIM + t], 0.f);
    }
    unsafeAtomicAdd(&out[curg * FDIM + t], acc);
}

// ---------------------------------------------------------------------------
extern "C" void kernel_launch(void* const* d_in, const int* in_sizes, int n_in,
                              void* d_out, int out_size, void* d_ws, size_t ws_size,
                              hipStream_t stream) {
    const float* x = (const float*)d_in[0];
    const int* ei = (const int*)d_in[1];
    const int* batch = (const int*)d_in[2];
    const float* W1 = (const float*)d_in[4];
    const float* b1 = (const float*)d_in[5];
    const float* W2 = (const float*)d_in[6];
    const float* b2 = (const float*)d_in[7];

    const int N = in_sizes[2];
    const int E = in_sizes[1] / 2;
    const int* srcp = ei;
    const int* dstp = ei + E;

    float* ws = (float*)d_ws;
    const size_t NF = (size_t)N * FDIM;
    float* bufA = ws;                      // N*128  (xw)
    float* bufB = bufA + NF;               // N*128  (aggregated / h)
    float* dinv = bufB + NF;               // N
    int* cnt = (int*)(dinv + N);           // N      <- memset from here
    int* counter = cnt + N;                // 1      <- memset to here
    float* mean = (float*)(counter + 1);   // 128
    float* rstd = mean + FDIM;             // 128
    float* bias0 = rstd + FDIM;            // 128
    unsigned short* WT1bf = (unsigned short*)(bias0 + FDIM);  // 128*128 bf16
    unsigned short* WT2bf = WT1bf + FDIM * FDIM;              // 128*128 bf16
    int* start = (int*)(WT2bf + FDIM * FDIM);  // N
    int* wcur = start + N;                 // N
    int* esrc = wcur + N;                  // E
    float* ecoef = (float*)(esrc + E);     // E
    // partials (512*256 f32 = 512 KB) aliased onto esrc/ecoef space: dead
    // before fill_edges runs.
    float* partials = (float*)esrc;
    const int STAT_BLOCKS = 512;

    hipMemsetAsync(cnt, 0, ((size_t)N + 1) * sizeof(int), stream);
    hipMemsetAsync(d_out, 0, (size_t)out_size * sizeof(float), stream);

    col_stats_kernel<<<STAT_BLOCKS, 256, 0, stream>>>(x, N, partials);
    finalize_stats<<<1, 1024, 0, stream>>>(partials, STAT_BLOCKS, N, mean, rstd);
    prep_wt<<<1, FDIM, 0, stream>>>(W1, mean, rstd, WT1bf, bias0);
    prep_wt<<<1, FDIM, 0, stream>>>(W2, nullptr, nullptr, WT2bf, nullptr);
    deg_count<<<(E + 255) / 256, 256, 0, stream>>>(dstp, E, cnt);
    dinv_kernel<<<(N + 255) / 256, 256, 0, stream>>>(cnt, dinv, N);
    alloc_offsets<<<(N + 255) / 256, 256, 0, stream>>>(cnt, N, start, wcur, counter);
    fill_edges<<<(E + 255) / 256, 256, 0, stream>>>(srcp, dstp, dinv, E, wcur, esrc, ecoef);

    const int gemmGrid = (N + 63) / 64;
    const int aggGrid = (N + 7) / 8;

    // ---- layer 1 (standardization folded into WT1bf/bias0)
    gemm_mfma<false><<<gemmGrid, 256, 0, stream>>>(x, WT1bf, bias0, bufA, N);
    aggregate<<<aggGrid, 256, 0, stream>>>(bufA, dinv, start, cnt, esrc, ecoef, b1, bufB, N);

    // ---- layer 2 (relu fused into GEMM stage)
    gemm_mfma<true><<<gemmGrid, 256, 0, stream>>>(bufB, WT2bf, nullptr, bufA, N);
    aggregate<<<aggGrid, 256, 0, stream>>>(bufA, dinv, start, cnt, esrc, ecoef, b2, bufB, N);

    // ---- pool (relu fused into load)
    pool_kernel<<<1024, FDIM, 0, stream>>>(bufB, batch, (float*)d_out, N);
}

// Round 5
// 512.618 us; speedup vs baseline: 2.5923x; 1.3892x over previous
//
#include <hip/hip_runtime.h>

#define FDIM 128  // feature dim == hidden dim

typedef __attribute__((ext_vector_type(8))) short short8;   // 8 bf16 (4 VGPRs)
typedef __attribute__((ext_vector_type(4))) float f32x4;    // MFMA accumulator

__device__ inline unsigned short f2bf(float f) {  // round-to-nearest-even
    unsigned int u = __float_as_uint(f);
    unsigned int r = u + 0x7FFFu + ((u >> 16) & 1u);
    return (unsigned short)(r >> 16);
}
__device__ inline float bf2f(unsigned short b) {
    return __uint_as_float((unsigned int)b << 16);
}

// ---------------------------------------------------------------------------
// 1) per-column sum/sumsq — grid float4 sweep, block LDS reduce, plain stores
//    of per-block partials (atomic-free).
__global__ __launch_bounds__(256) void col_stats_kernel(const float* __restrict__ x, int N,
                                                        float* __restrict__ partials) {
    const int c4 = threadIdx.x & 31;   // column group (4 cols)
    const int rg = threadIdx.x >> 5;   // row group 0..7
    float4 s = make_float4(0.f, 0.f, 0.f, 0.f);
    float4 q = make_float4(0.f, 0.f, 0.f, 0.f);
    for (long r = (long)blockIdx.x * 8 + rg; r < N; r += (long)gridDim.x * 8) {
        float4 v = ((const float4*)x)[r * 32 + c4];
        s.x += v.x; s.y += v.y; s.z += v.z; s.w += v.w;
        q.x += v.x * v.x; q.y += v.y * v.y; q.z += v.z * v.z; q.w += v.w * v.w;
    }
    __shared__ float red[8][32][8];  // 8 KB
    float* p = red[rg][c4];
    p[0] = s.x; p[1] = s.y; p[2] = s.z; p[3] = s.w;
    p[4] = q.x; p[5] = q.y; p[6] = q.z; p[7] = q.w;
    __syncthreads();
    if (rg == 0) {
#pragma unroll
        for (int g = 1; g < 8; ++g) {
            const float* o = red[g][c4];
#pragma unroll
            for (int j = 0; j < 8; ++j) red[0][c4][j] += o[j];
        }
        const float* r0 = red[0][c4];
        float* out = &partials[(size_t)blockIdx.x * 256];
        ((float4*)out)[c4] = make_float4(r0[0], r0[1], r0[2], r0[3]);
        ((float4*)(out + 128))[c4] = make_float4(r0[4], r0[5], r0[6], r0[7]);
    }
}

// 2) reduce partials -> mean / rstd (ddof=1)
__global__ __launch_bounds__(1024) void finalize_stats(const float* __restrict__ partials,
                                                       int nblk, int N,
                                                       float* __restrict__ mean,
                                                       float* __restrict__ rstd) {
    __shared__ float sh[8][2][FDIM];
    int g = threadIdx.x >> 7;
    int j = threadIdx.x & 127;
    float s = 0.f, q = 0.f;
    for (int b = g; b < nblk; b += 8) {
        s += partials[(size_t)b * 256 + j];
        q += partials[(size_t)b * 256 + 128 + j];
    }
    sh[g][0][j] = s;
    sh[g][1][j] = q;
    __syncthreads();
    if (g == 0) {
#pragma unroll
        for (int k = 1; k < 8; ++k) { s += sh[k][0][j]; q += sh[k][1][j]; }
        float m = s / (float)N;
        float var = (q - (float)N * m * m) / (float)(N - 1);
        mean[j] = m;
        rstd[j] = rsqrtf(var);
    }
}

// 3) both weight transposes in one launch: block 0 = W1 (scaled, +bias0), block 1 = W2
__global__ void prep_wt2(const float* __restrict__ W1, const float* __restrict__ W2,
                         const float* __restrict__ mean, const float* __restrict__ rstd,
                         unsigned short* __restrict__ WT1, unsigned short* __restrict__ WT2,
                         float* __restrict__ bias0) {
    int h = threadIdx.x;  // 0..127
    if (blockIdx.x == 0) {
        float acc = 0.f;
        for (int j = 0; j < FDIM; ++j) {
            float w = W1[j * FDIM + h] * rstd[j];
            WT1[h * FDIM + j] = f2bf(w);
            acc += mean[j] * w;
        }
        bias0[h] = -acc;
    } else {
        for (int j = 0; j < FDIM; ++j) WT2[h * FDIM + j] = f2bf(W2[j * FDIM + h]);
    }
}

// 4) degree count at dst (int)
__global__ void deg_count(const int* __restrict__ dst, int E, int* __restrict__ cnt) {
    int e = blockIdx.x * blockDim.x + threadIdx.x;
    if (e < E) atomicAdd(&cnt[dst[e]], 1);
}

// 5) contiguous per-node edge ranges + dinv (fused)
__global__ __launch_bounds__(256) void alloc_offsets(const int* __restrict__ cnt, int N,
                                                     int* __restrict__ start,
                                                     int* __restrict__ wcur,
                                                     int* __restrict__ counter,
                                                     float* __restrict__ dinv) {
    __shared__ int sh[256];
    __shared__ int base;
    int i = blockIdx.x * 256 + threadIdx.x;
    int v = (i < N) ? cnt[i] : 0;
    sh[threadIdx.x] = v;
    __syncthreads();
    for (int off = 1; off < 256; off <<= 1) {
        int t = (threadIdx.x >= off) ? sh[threadIdx.x - off] : 0;
        __syncthreads();
        sh[threadIdx.x] += t;
        __syncthreads();
    }
    if (threadIdx.x == 255) base = atomicAdd(counter, sh[255]);
    __syncthreads();
    int excl = base + sh[threadIdx.x] - v;
    if (i < N) {
        start[i] = excl;
        wcur[i] = excl;
        dinv[i] = rsqrtf((float)v + 1.0f);
    }
}

// 6) bucket edges by dst; one 8B store per edge: {src, coef bits}
__global__ void fill_edges(const int* __restrict__ src, const int* __restrict__ dst,
                           const float* __restrict__ dinv, int E,
                           int* __restrict__ wcur, int2* __restrict__ edata) {
    int e = blockIdx.x * blockDim.x + threadIdx.x;
    if (e >= E) return;
    int s = src[e], d = dst[e];
    int pos = atomicAdd(&wcur[d], 1);
    edata[pos] = make_int2(s, __float_as_int(dinv[s] * dinv[d]));
}

// ---------------------------------------------------------------------------
// 7) bf16 MFMA GEMM: C_bf16[M x 128] = A[M x 128] @ W[128 x 128] (+ bias)
//    T = float (layer 1 raw x; standardization folded into WT/bias) or
//    ushort (layer 2 bf16 h, already relu'd by aggregate).
template <typename T>
__global__ __launch_bounds__(256) void gemm_mfma(const T* __restrict__ A,
                                                 const unsigned short* __restrict__ WT,
                                                 const float* __restrict__ bias,
                                                 unsigned short* __restrict__ C, int M) {
    constexpr int LDA = 136;  // bf16 elems; b128 reads land 8 lanes/bank-group
    __shared__ unsigned short Alds[64 * LDA];    // 17.4 KB
    __shared__ unsigned short Wlds[FDIM * LDA];  // 34.8 KB
    const int tid = threadIdx.x;
    const int row0 = blockIdx.x * 64;

    // stage WT -> LDS, 16B chunks
    for (int i = tid; i < FDIM * 16; i += 256) {
        int r = i >> 4, g = i & 15;
        *(int4*)&Wlds[r * LDA + g * 8] = *(const int4*)&WT[r * FDIM + g * 8];
    }
    if constexpr (sizeof(T) == 4) {
        // fp32 input: convert to bf16 while staging
        for (int i = tid; i < 64 * 32; i += 256) {
            int r = i >> 5, c4 = i & 31;
            int row = row0 + r;
            float4 v = make_float4(0.f, 0.f, 0.f, 0.f);
            if (row < M) v = ((const float4*)A)[(size_t)row * 32 + c4];
            ushort4 p;
            p.x = f2bf(v.x); p.y = f2bf(v.y); p.z = f2bf(v.z); p.w = f2bf(v.w);
            *(ushort4*)&Alds[r * LDA + c4 * 4] = p;
        }
    } else {
        // bf16 input: straight 16B copies
        for (int i = tid; i < 64 * 16; i += 256) {
            int r = i >> 4, g = i & 15;
            int row = row0 + r;
            int4 v = make_int4(0, 0, 0, 0);
            if (row < M) v = *(const int4*)&A[(size_t)row * FDIM + g * 8];
            *(int4*)&Alds[r * LDA + g * 8] = v;
        }
    }
    __syncthreads();

    const int lane = tid & 63;
    const int wave = tid >> 6;
    const int m16 = lane & 15;
    const int quad = lane >> 4;

    f32x4 acc[8];
#pragma unroll
    for (int t = 0; t < 8; ++t) acc[t] = (f32x4){0.f, 0.f, 0.f, 0.f};

    const unsigned short* Abase = &Alds[(wave * 16 + m16) * LDA + quad * 8];
    const unsigned short* Wbase = &Wlds[m16 * LDA + quad * 8];
#pragma unroll
    for (int s = 0; s < 4; ++s) {
        short8 a = *(const short8*)&Abase[s * 32];
#pragma unroll
        for (int t = 0; t < 8; ++t) {
            short8 b = *(const short8*)&Wbase[t * 16 * LDA + s * 32];
            acc[t] = __builtin_amdgcn_mfma_f32_16x16x32_bf16(a, b, acc[t], 0, 0, 0);
        }
    }

    // epilogue: C/D layout col=lane&15, row=quad*4+reg; store bf16
#pragma unroll
    for (int t = 0; t < 8; ++t) {
        float bv = bias ? bias[t * 16 + m16] : 0.f;
#pragma unroll
        for (int i = 0; i < 4; ++i) {
            int r = row0 + wave * 16 + quad * 4 + i;
            if (r < M) C[(size_t)r * FDIM + t * 16 + m16] = f2bf(acc[t][i] + bv);
        }
    }
}

// ---------------------------------------------------------------------------
// 8) aggregation (bf16 in, bf16 out, fp32 accum), ReLU fused into the store
//    (both consumers of each layer's output apply ReLU).
//    out[d] = relu(xw[d]*dinv[d]^2 + b + sum_{e:dst=d} xw[src]*coef)
__global__ __launch_bounds__(256) void aggregate(const unsigned short* __restrict__ xw,
                                                 const float* __restrict__ dinv,
                                                 const int* __restrict__ start,
                                                 const int* __restrict__ cnt,
                                                 const int2* __restrict__ edata,
                                                 const float* __restrict__ bvec,
                                                 unsigned short* __restrict__ out, int N) {
    int node = blockIdx.x * 8 + (threadIdx.x >> 5);
    if (node >= N) return;
    int c4 = threadIdx.x & 31;  // 4-col group
    float dv = dinv[node];
    float d2 = dv * dv;
    float4 b = ((const float4*)bvec)[c4];
    ushort4 sv = *(const ushort4*)&xw[(size_t)node * FDIM + c4 * 4];
    float4 acc = make_float4(fmaf(bf2f(sv.x), d2, b.x), fmaf(bf2f(sv.y), d2, b.y),
                             fmaf(bf2f(sv.z), d2, b.z), fmaf(bf2f(sv.w), d2, b.w));
    int s0 = start[node];
    int s1 = s0 + cnt[node];
    for (int j = s0; j < s1; ++j) {
        int2 ed = edata[j];  // broadcast within the node's 32 lanes
        float c = __int_as_float(ed.y);
        ushort4 u = *(const ushort4*)&xw[(size_t)ed.x * FDIM + c4 * 4];
        acc.x = fmaf(bf2f(u.x), c, acc.x);
        acc.y = fmaf(bf2f(u.y), c, acc.y);
        acc.z = fmaf(bf2f(u.z), c, acc.z);
        acc.w = fmaf(bf2f(u.w), c, acc.w);
    }
    ushort4 o;
    o.x = f2bf(fmaxf(acc.x, 0.f));
    o.y = f2bf(fmaxf(acc.y, 0.f));
    o.z = f2bf(fmaxf(acc.z, 0.f));
    o.w = f2bf(fmaxf(acc.w, 0.f));
    *(ushort4*)&out[(size_t)node * FDIM + c4 * 4] = o;
}

// 9) pooled = segment_sum(h, batch) — h already relu'd; batch sorted.
//    Two independent 128-lane units per block; running-acc + flush-on-change.
__global__ __launch_bounds__(256) void pool_kernel(const unsigned short* __restrict__ h,
                                                   const int* __restrict__ batch,
                                                   float* __restrict__ out, int N,
                                                   int chunk) {
    int unit = blockIdx.x * 2 + (threadIdx.x >> 7);
    int t = threadIdx.x & 127;  // column
    long r0 = (long)unit * chunk;
    if (r0 >= N) return;
    long r1 = min(r0 + (long)chunk, (long)N);
    float acc = 0.f;
    int curg = batch[r0];
    for (long r = r0; r < r1; ++r) {
        int g = batch[r];
        if (g != curg) {
            unsafeAtomicAdd(&out[curg * FDIM + t], acc);
            acc = 0.f;
            curg = g;
        }
        acc += bf2f(h[r * FDIM + t]);
    }
    unsafeAtomicAdd(&out[curg * FDIM + t], acc);
}

// ---------------------------------------------------------------------------
extern "C" void kernel_launch(void* const* d_in, const int* in_sizes, int n_in,
                              void* d_out, int out_size, void* d_ws, size_t ws_size,
                              hipStream_t stream) {
    const float* x = (const float*)d_in[0];
    const int* ei = (const int*)d_in[1];
    const int* batch = (const int*)d_in[2];
    const float* W1 = (const float*)d_in[4];
    const float* b1 = (const float*)d_in[5];
    const float* W2 = (const float*)d_in[6];
    const float* b2 = (const float*)d_in[7];

    const int N = in_sizes[2];
    const int E = in_sizes[1] / 2;
    const int* srcp = ei;
    const int* dstp = ei + E;

    const size_t NF = (size_t)N * FDIM;
    unsigned short* bufA = (unsigned short*)d_ws;  // N*128 bf16 (xw)
    unsigned short* bufB = bufA + NF;              // N*128 bf16 (h)
    int* cnt = (int*)(bufB + NF);                  // N   <- memset from here
    int* counter = cnt + N;                        // 4 (1 used + pad) <- to here
    float* dinv = (float*)(counter + 4);           // N
    int* start = (int*)(dinv + N);                 // N
    int* wcur = start + N;                         // N
    float* mean = (float*)(wcur + N);              // 128
    float* rstd = mean + FDIM;                     // 128
    float* bias0 = rstd + FDIM;                    // 128
    unsigned short* WT1 = (unsigned short*)(bias0 + FDIM);  // 128*128 bf16
    unsigned short* WT2 = WT1 + FDIM * FDIM;                // 128*128 bf16
    int2* edata = (int2*)(WT2 + FDIM * FDIM);      // E x {src, coef}
    // partials (512*256 f32 = 512 KB) aliased onto edata: dead before fill_edges
    float* partials = (float*)edata;
    const int STAT_BLOCKS = 512;

    hipMemsetAsync(cnt, 0, ((size_t)N + 4) * sizeof(int), stream);
    hipMemsetAsync(d_out, 0, (size_t)out_size * sizeof(float), stream);

    col_stats_kernel<<<STAT_BLOCKS, 256, 0, stream>>>(x, N, partials);
    finalize_stats<<<1, 1024, 0, stream>>>(partials, STAT_BLOCKS, N, mean, rstd);
    prep_wt2<<<2, FDIM, 0, stream>>>(W1, W2, mean, rstd, WT1, WT2, bias0);
    deg_count<<<(E + 255) / 256, 256, 0, stream>>>(dstp, E, cnt);
    alloc_offsets<<<(N + 255) / 256, 256, 0, stream>>>(cnt, N, start, wcur, counter, dinv);
    fill_edges<<<(E + 255) / 256, 256, 0, stream>>>(srcp, dstp, dinv, E, wcur, edata);

    const int gemmGrid = (N + 63) / 64;
    const int aggGrid = (N + 7) / 8;

    // ---- layer 1 (standardization folded into WT1/bias0; relu in aggregate)
    gemm_mfma<float><<<gemmGrid, 256, 0, stream>>>(x, WT1, bias0, bufA, N);
    aggregate<<<aggGrid, 256, 0, stream>>>(bufA, dinv, start, cnt, edata, b1, bufB, N);

    // ---- layer 2
    gemm_mfma<unsigned short><<<gemmGrid, 256, 0, stream>>>(bufB, WT2, nullptr, bufA, N);
    aggregate<<<aggGrid, 256, 0, stream>>>(bufA, dinv, start, cnt, edata, b2, bufB, N);

    // ---- pool (h already relu'd)
    const int POOL_BLOCKS = 2048;
    int chunk = (N + POOL_BLOCKS * 2 - 1) / (POOL_BLOCKS * 2);
    pool_kernel<<<POOL_BLOCKS, 256, 0, stream>>>(bufB, batch, (float*)d_out, N, chunk);
}

// Round 6
// 449.879 us; speedup vs baseline: 2.9538x; 1.1395x over previous
//
#include <hip/hip_runtime.h>

#define FDIM 128  // feature dim == hidden dim

typedef __attribute__((ext_vector_type(8))) short short8;   // 8 bf16 (4 VGPRs)
typedef __attribute__((ext_vector_type(4))) float f32x4;    // MFMA accumulator

__device__ inline unsigned short f2bf(float f) {  // round-to-nearest-even
    unsigned int u = __float_as_uint(f);
    unsigned int r = u + 0x7FFFu + ((u >> 16) & 1u);
    return (unsigned short)(r >> 16);
}
__device__ inline float bf2f(unsigned short b) {
    return __uint_as_float((unsigned int)b << 16);
}
__device__ inline void bf8_fma(short8 v, float c, float* acc) {
#pragma unroll
    for (int k = 0; k < 8; ++k)
        acc[k] = fmaf(bf2f(((const unsigned short*)&v)[k]), c, acc[k]);
}

// ---------------------------------------------------------------------------
// 1) per-column sum/sumsq — grid float4 sweep, block LDS reduce, plain stores
__global__ __launch_bounds__(256) void col_stats_kernel(const float* __restrict__ x, int N,
                                                        float* __restrict__ partials) {
    const int c4 = threadIdx.x & 31;
    const int rg = threadIdx.x >> 5;
    float4 s = make_float4(0.f, 0.f, 0.f, 0.f);
    float4 q = make_float4(0.f, 0.f, 0.f, 0.f);
    for (long r = (long)blockIdx.x * 8 + rg; r < N; r += (long)gridDim.x * 8) {
        float4 v = ((const float4*)x)[r * 32 + c4];
        s.x += v.x; s.y += v.y; s.z += v.z; s.w += v.w;
        q.x += v.x * v.x; q.y += v.y * v.y; q.z += v.z * v.z; q.w += v.w * v.w;
    }
    __shared__ float red[8][32][8];
    float* p = red[rg][c4];
    p[0] = s.x; p[1] = s.y; p[2] = s.z; p[3] = s.w;
    p[4] = q.x; p[5] = q.y; p[6] = q.z; p[7] = q.w;
    __syncthreads();
    if (rg == 0) {
#pragma unroll
        for (int g = 1; g < 8; ++g) {
            const float* o = red[g][c4];
#pragma unroll
            for (int j = 0; j < 8; ++j) red[0][c4][j] += o[j];
        }
        const float* r0 = red[0][c4];
        float* out = &partials[(size_t)blockIdx.x * 256];
        ((float4*)out)[c4] = make_float4(r0[0], r0[1], r0[2], r0[3]);
        ((float4*)(out + 128))[c4] = make_float4(r0[4], r0[5], r0[6], r0[7]);
    }
}

// 2) reduce partials -> mean / rstd (ddof=1)
__global__ __launch_bounds__(1024) void finalize_stats(const float* __restrict__ partials,
                                                       int nblk, int N,
                                                       float* __restrict__ mean,
                                                       float* __restrict__ rstd) {
    __shared__ float sh[8][2][FDIM];
    int g = threadIdx.x >> 7;
    int j = threadIdx.x & 127;
    float s = 0.f, q = 0.f;
    for (int b = g; b < nblk; b += 8) {
        s += partials[(size_t)b * 256 + j];
        q += partials[(size_t)b * 256 + 128 + j];
    }
    sh[g][0][j] = s;
    sh[g][1][j] = q;
    __syncthreads();
    if (g == 0) {
#pragma unroll
        for (int k = 1; k < 8; ++k) { s += sh[k][0][j]; q += sh[k][1][j]; }
        float m = s / (float)N;
        float var = (q - (float)N * m * m) / (float)(N - 1);
        mean[j] = m;
        rstd[j] = rsqrtf(var);
    }
}

// 3) weight transposes, j-sliced across 16 blocks. Blocks 0-7: W1 (scaled,
//    bias0 partials via atomic into zeroed bias0). Blocks 8-15: W2.
__global__ void prep_wt(const float* __restrict__ W1, const float* __restrict__ W2,
                        const float* __restrict__ mean, const float* __restrict__ rstd,
                        unsigned short* __restrict__ WT1, unsigned short* __restrict__ WT2,
                        float* __restrict__ bias0) {
    int h = threadIdx.x;  // 0..127
    int b = blockIdx.x;
    if (b < 8) {
        float acc = 0.f;
#pragma unroll
        for (int jj = 0; jj < 16; ++jj) {
            int j = b * 16 + jj;
            float w = W1[j * FDIM + h] * rstd[j];
            WT1[h * FDIM + j] = f2bf(w);
            acc += mean[j] * w;
        }
        unsafeAtomicAdd(&bias0[h], -acc);
    } else {
#pragma unroll
        for (int jj = 0; jj < 16; ++jj) {
            int j = (b - 8) * 16 + jj;
            WT2[h * FDIM + j] = f2bf(W2[j * FDIM + h]);
        }
    }
}

// 4) degree count at dst (int)
__global__ void deg_count(const int* __restrict__ dst, int E, int* __restrict__ cnt) {
    int e = blockIdx.x * blockDim.x + threadIdx.x;
    if (e < E) atomicAdd(&cnt[dst[e]], 1);
}

// 5) contiguous per-node edge ranges + dinv (fused)
__global__ __launch_bounds__(256) void alloc_offsets(const int* __restrict__ cnt, int N,
                                                     int* __restrict__ start,
                                                     int* __restrict__ wcur,
                                                     int* __restrict__ counter,
                                                     float* __restrict__ dinv) {
    __shared__ int sh[256];
    __shared__ int base;
    int i = blockIdx.x * 256 + threadIdx.x;
    int v = (i < N) ? cnt[i] : 0;
    sh[threadIdx.x] = v;
    __syncthreads();
    for (int off = 1; off < 256; off <<= 1) {
        int t = (threadIdx.x >= off) ? sh[threadIdx.x - off] : 0;
        __syncthreads();
        sh[threadIdx.x] += t;
        __syncthreads();
    }
    if (threadIdx.x == 255) base = atomicAdd(counter, sh[255]);
    __syncthreads();
    int excl = base + sh[threadIdx.x] - v;
    if (i < N) {
        start[i] = excl;
        wcur[i] = excl;
        dinv[i] = rsqrtf((float)v + 1.0f);
    }
}

// 6) bucket edges by dst; one 8B store per edge: {src, coef bits}
__global__ void fill_edges(const int* __restrict__ src, const int* __restrict__ dst,
                           const float* __restrict__ dinv, int E,
                           int* __restrict__ wcur, int2* __restrict__ edata) {
    int e = blockIdx.x * blockDim.x + threadIdx.x;
    if (e >= E) return;
    int s = src[e], d = dst[e];
    int pos = atomicAdd(&wcur[d], 1);
    edata[pos] = make_int2(s, __float_as_int(dinv[s] * dinv[d]));
}

// ---------------------------------------------------------------------------
// 7) bf16 MFMA GEMM: C_bf16[M x 128] = A[M x 128] @ W[128 x 128] (+ bias)
template <typename T>
__global__ __launch_bounds__(256) void gemm_mfma(const T* __restrict__ A,
                                                 const unsigned short* __restrict__ WT,
                                                 const float* __restrict__ bias,
                                                 unsigned short* __restrict__ C, int M) {
    constexpr int LDA = 136;
    __shared__ unsigned short Alds[64 * LDA];
    __shared__ unsigned short Wlds[FDIM * LDA];
    const int tid = threadIdx.x;
    const int row0 = blockIdx.x * 64;

    for (int i = tid; i < FDIM * 16; i += 256) {
        int r = i >> 4, g = i & 15;
        *(int4*)&Wlds[r * LDA + g * 8] = *(const int4*)&WT[r * FDIM + g * 8];
    }
    if constexpr (sizeof(T) == 4) {
        for (int i = tid; i < 64 * 32; i += 256) {
            int r = i >> 5, c4 = i & 31;
            int row = row0 + r;
            float4 v = make_float4(0.f, 0.f, 0.f, 0.f);
            if (row < M) v = ((const float4*)A)[(size_t)row * 32 + c4];
            ushort4 p;
            p.x = f2bf(v.x); p.y = f2bf(v.y); p.z = f2bf(v.z); p.w = f2bf(v.w);
            *(ushort4*)&Alds[r * LDA + c4 * 4] = p;
        }
    } else {
        for (int i = tid; i < 64 * 16; i += 256) {
            int r = i >> 4, g = i & 15;
            int row = row0 + r;
            int4 v = make_int4(0, 0, 0, 0);
            if (row < M) v = *(const int4*)&A[(size_t)row * FDIM + g * 8];
            *(int4*)&Alds[r * LDA + g * 8] = v;
        }
    }
    __syncthreads();

    const int lane = tid & 63;
    const int wave = tid >> 6;
    const int m16 = lane & 15;
    const int quad = lane >> 4;

    f32x4 acc[8];
#pragma unroll
    for (int t = 0; t < 8; ++t) acc[t] = (f32x4){0.f, 0.f, 0.f, 0.f};

    const unsigned short* Abase = &Alds[(wave * 16 + m16) * LDA + quad * 8];
    const unsigned short* Wbase = &Wlds[m16 * LDA + quad * 8];
#pragma unroll
    for (int s = 0; s < 4; ++s) {
        short8 a = *(const short8*)&Abase[s * 32];
#pragma unroll
        for (int t = 0; t < 8; ++t) {
            short8 b = *(const short8*)&Wbase[t * 16 * LDA + s * 32];
            acc[t] = __builtin_amdgcn_mfma_f32_16x16x32_bf16(a, b, acc[t], 0, 0, 0);
        }
    }

#pragma unroll
    for (int t = 0; t < 8; ++t) {
        float bv = bias ? bias[t * 16 + m16] : 0.f;
#pragma unroll
        for (int i = 0; i < 4; ++i) {
            int r = row0 + wave * 16 + quad * 4 + i;
            if (r < M) C[(size_t)r * FDIM + t * 16 + m16] = f2bf(acc[t][i] + bv);
        }
    }
}

// ---------------------------------------------------------------------------
// 8) aggregation (bf16 in/out, fp32 accum, relu on store).
//    16 lanes/node (ushort8 per lane): 4 independent node streams per wave.
//    Edge loop 4x-unrolled: 4 independent gathers in flight per batch.
__global__ __launch_bounds__(256) void aggregate(const unsigned short* __restrict__ xw,
                                                 const float* __restrict__ dinv,
                                                 const int* __restrict__ start,
                                                 const int* __restrict__ cnt,
                                                 const int2* __restrict__ edata,
                                                 const float* __restrict__ bvec,
                                                 unsigned short* __restrict__ out, int N) {
    int node = blockIdx.x * 16 + (threadIdx.x >> 4);
    if (node >= N) return;
    const int l8 = threadIdx.x & 15;  // 8-col group
    float dv = dinv[node];
    float d2 = dv * dv;
    float4 b0 = ((const float4*)bvec)[l8 * 2];
    float4 b1 = ((const float4*)bvec)[l8 * 2 + 1];
    float acc[8] = {b0.x, b0.y, b0.z, b0.w, b1.x, b1.y, b1.z, b1.w};
    short8 sv = *(const short8*)&xw[(size_t)node * FDIM + l8 * 8];
    bf8_fma(sv, d2, acc);

    int j = start[node];
    const int s1 = j + cnt[node];
    for (; j + 4 <= s1; j += 4) {
        int2 e0 = edata[j], e1 = edata[j + 1], e2 = edata[j + 2], e3 = edata[j + 3];
        short8 u0 = *(const short8*)&xw[(size_t)e0.x * FDIM + l8 * 8];
        short8 u1 = *(const short8*)&xw[(size_t)e1.x * FDIM + l8 * 8];
        short8 u2 = *(const short8*)&xw[(size_t)e2.x * FDIM + l8 * 8];
        short8 u3 = *(const short8*)&xw[(size_t)e3.x * FDIM + l8 * 8];
        bf8_fma(u0, __int_as_float(e0.y), acc);
        bf8_fma(u1, __int_as_float(e1.y), acc);
        bf8_fma(u2, __int_as_float(e2.y), acc);
        bf8_fma(u3, __int_as_float(e3.y), acc);
    }
    for (; j < s1; ++j) {
        int2 ed = edata[j];
        short8 u = *(const short8*)&xw[(size_t)ed.x * FDIM + l8 * 8];
        bf8_fma(u, __int_as_float(ed.y), acc);
    }

    short8 o;
#pragma unroll
    for (int k = 0; k < 8; ++k)
        ((unsigned short*)&o)[k] = f2bf(fmaxf(acc[k], 0.f));
    *(short8*)&out[(size_t)node * FDIM + l8 * 8] = o;
}

// ---------------------------------------------------------------------------
// 9) pooled = segment_sum(h, batch). One wave per 32-row unit, 2 cols/lane.
//    batch sorted + G=64 over 200K rows: >98% of units span a single graph ->
//    fast path: endpoint check, straight sum, one atomic flush per col.
#define POOL_ROWS 32
__global__ __launch_bounds__(256) void pool_kernel(const unsigned short* __restrict__ h,
                                                   const int* __restrict__ batch,
                                                   float* __restrict__ out, int N) {
    int unit = blockIdx.x * 4 + (threadIdx.x >> 6);
    int lane = threadIdx.x & 63;  // cols [2*lane, 2*lane+1]
    long r0 = (long)unit * POOL_ROWS;
    if (r0 >= N) return;
    long r1 = min(r0 + (long)POOL_ROWS, (long)N);
    int g0 = batch[r0];
    int g1 = batch[r1 - 1];
    if (g0 == g1) {
        float a0 = 0.f, a1 = 0.f;
#pragma unroll
        for (int i = 0; i < POOL_ROWS; ++i) {
            long r = r0 + i;
            if (r < r1) {
                unsigned int v = *(const unsigned int*)&h[r * FDIM + lane * 2];
                a0 += bf2f((unsigned short)(v & 0xFFFF));
                a1 += bf2f((unsigned short)(v >> 16));
            }
        }
        unsafeAtomicAdd(&out[g0 * FDIM + lane * 2], a0);
        unsafeAtomicAdd(&out[g0 * FDIM + lane * 2 + 1], a1);
    } else {
        float a0 = 0.f, a1 = 0.f;
        int curg = g0;
        for (long r = r0; r < r1; ++r) {
            int g = batch[r];
            if (g != curg) {
                unsafeAtomicAdd(&out[curg * FDIM + lane * 2], a0);
                unsafeAtomicAdd(&out[curg * FDIM + lane * 2 + 1], a1);
                a0 = a1 = 0.f;
                curg = g;
            }
            unsigned int v = *(const unsigned int*)&h[r * FDIM + lane * 2];
            a0 += bf2f((unsigned short)(v & 0xFFFF));
            a1 += bf2f((unsigned short)(v >> 16));
        }
        unsafeAtomicAdd(&out[curg * FDIM + lane * 2], a0);
        unsafeAtomicAdd(&out[curg * FDIM + lane * 2 + 1], a1);
    }
}

// ---------------------------------------------------------------------------
extern "C" void kernel_launch(void* const* d_in, const int* in_sizes, int n_in,
                              void* d_out, int out_size, void* d_ws, size_t ws_size,
                              hipStream_t stream) {
    const float* x = (const float*)d_in[0];
    const int* ei = (const int*)d_in[1];
    const int* batch = (const int*)d_in[2];
    const float* W1 = (const float*)d_in[4];
    const float* b1 = (const float*)d_in[5];
    const float* W2 = (const float*)d_in[6];
    const float* b2 = (const float*)d_in[7];

    const int N = in_sizes[2];
    const int E = in_sizes[1] / 2;
    const int* srcp = ei;
    const int* dstp = ei + E;

    const size_t NF = (size_t)N * FDIM;
    unsigned short* bufA = (unsigned short*)d_ws;  // N*128 bf16 (xw)
    unsigned short* bufB = bufA + NF;              // N*128 bf16 (h)
    int* cnt = (int*)(bufB + NF);                  // N      <- memset from here
    int* counter = cnt + N;                        // 4
    float* bias0 = (float*)(counter + 4);          // 128    <- memset to here
    float* dinv = bias0 + FDIM;                    // N
    int* start = (int*)(dinv + N);                 // N
    int* wcur = start + N;                         // N
    float* mean = (float*)(wcur + N);              // 128
    float* rstd = mean + FDIM;                     // 128
    unsigned short* WT1 = (unsigned short*)(rstd + FDIM);  // 128*128 bf16
    unsigned short* WT2 = WT1 + FDIM * FDIM;               // 128*128 bf16
    int2* edata = (int2*)(WT2 + FDIM * FDIM);      // E x {src, coef}
    float* partials = (float*)edata;               // aliased; dead before fill_edges
    const int STAT_BLOCKS = 512;

    hipMemsetAsync(cnt, 0, ((size_t)N + 4 + FDIM) * sizeof(int), stream);
    hipMemsetAsync(d_out, 0, (size_t)out_size * sizeof(float), stream);

    col_stats_kernel<<<STAT_BLOCKS, 256, 0, stream>>>(x, N, partials);
    finalize_stats<<<1, 1024, 0, stream>>>(partials, STAT_BLOCKS, N, mean, rstd);
    prep_wt<<<16, FDIM, 0, stream>>>(W1, W2, mean, rstd, WT1, WT2, bias0);
    deg_count<<<(E + 255) / 256, 256, 0, stream>>>(dstp, E, cnt);
    alloc_offsets<<<(N + 255) / 256, 256, 0, stream>>>(cnt, N, start, wcur, counter, dinv);
    fill_edges<<<(E + 255) / 256, 256, 0, stream>>>(srcp, dstp, dinv, E, wcur, edata);

    const int gemmGrid = (N + 63) / 64;
    const int aggGrid = (N + 15) / 16;

    // ---- layer 1 (standardization folded into WT1/bias0; relu in aggregate)
    gemm_mfma<float><<<gemmGrid, 256, 0, stream>>>(x, WT1, bias0, bufA, N);
    aggregate<<<aggGrid, 256, 0, stream>>>(bufA, dinv, start, cnt, edata, b1, bufB, N);

    // ---- layer 2
    gemm_mfma<unsigned short><<<gemmGrid, 256, 0, stream>>>(bufB, WT2, nullptr, bufA, N);
    aggregate<<<aggGrid, 256, 0, stream>>>(bufA, dinv, start, cnt, edata, b2, bufB, N);

    // ---- pool (h already relu'd)
    const int poolUnits = (N + POOL_ROWS - 1) / POOL_ROWS;
    pool_kernel<<<(poolUnits + 3) / 4, 256, 0, stream>>>(bufB, batch, (float*)d_out, N);
}